// Round 23
// baseline (175.940 us; speedup 1.0000x reference)
//
#include <hip/hip_runtime.h>
#include <stdint.h>

#define DIM   768
#define NH    12
#define HD    64
#define NT    196      // 14*14 tokens
#define M_ROWS 12544   // 64*196

typedef __attribute__((ext_vector_type(8))) short bf16x8;
typedef __attribute__((ext_vector_type(4))) float f32x4;

__device__ __forceinline__ float b2f(short s) {
  union { unsigned u; float f; } c;
  c.u = ((unsigned)(unsigned short)s) << 16;
  return c.f;
}
__device__ __forceinline__ short f2b(float f) {
  union { float f; unsigned u; } c; c.f = f;
  unsigned u = c.u;
  u += 0x7fffu + ((u >> 16) & 1u);   // RNE
  return (short)(u >> 16);
}

__device__ __forceinline__ f32x4 mfma16(bf16x8 a, bf16x8 b, f32x4 c) {
  return __builtin_amdgcn_mfma_f32_16x16x32_bf16(a, b, c, 0, 0, 0);
}

__device__ __forceinline__ void g2lds16(const short* g, short* l) {
  __builtin_amdgcn_global_load_lds(
      (const __attribute__((address_space(1))) void*)g,
      (__attribute__((address_space(3))) void*)l, 16, 0, 0);
}

// -------- kernel 1: fused pre-stage -----------------------------------------
struct CvtArgs { const float* src[4]; int n4[4]; int off[4]; };

__global__ __launch_bounds__(256) void k_pre(
    const float* __restrict__ x, const float* __restrict__ la_q,
    const float* __restrict__ la_v, float* __restrict__ xa,
    short* __restrict__ xb, CvtArgs a, short* __restrict__ cvtdst)
{
  const int bid = blockIdx.x;
  const int tid = threadIdx.x;
  if (bid >= 3136) {
    const int gt = (bid - 3136) * 256 + tid;
    const int stride = 512 * 256;
    #pragma unroll
    for (int s = 0; s < 4; ++s) {
      const float4* sp = (const float4*)a.src[s];
      short4* dp = (short4*)(cvtdst + a.off[s]);
      const int n4 = a.n4[s];
      for (int i = gt; i < n4; i += stride) {
        float4 v = sp[i];
        short4 o = { f2b(v.x), f2b(v.y), f2b(v.z), f2b(v.w) };
        dp[i] = o;
      }
    }
    return;
  }
  __shared__ float sla[8][DIM];
  for (int i = tid; i < 8 * DIM; i += 256) {
    int j = i / DIM, c = i - j * DIM;
    sla[j][c] = (j < 4) ? la_q[j * DIM + c] : la_v[(j - 4) * DIM + c];
  }
  __syncthreads();
  const int lane = tid & 63, wid = tid >> 6;
  const int m = bid * 4 + wid;
  const float4* xr = (const float4*)(x + (size_t)m * DIM);
  short4* xbr = (short4*)(xb + (size_t)m * DIM);
  float s[8] = {};
  #pragma unroll
  for (int i = 0; i < 3; ++i) {
    float4 xv = xr[lane + 64 * i];
    short4 o = { f2b(xv.x), f2b(xv.y), f2b(xv.z), f2b(xv.w) };
    xbr[lane + 64 * i] = o;
    int c = (lane + 64 * i) * 4;
    #pragma unroll
    for (int j = 0; j < 8; ++j)
      s[j] += xv.x * sla[j][c] + xv.y * sla[j][c + 1]
            + xv.z * sla[j][c + 2] + xv.w * sla[j][c + 3];
  }
  #pragma unroll
  for (int j = 0; j < 8; ++j) {
    #pragma unroll
    for (int off = 32; off; off >>= 1) s[j] += __shfl_xor(s[j], off);
  }
  if (lane == 0) {
    float* o = xa + m * 8;
    #pragma unroll
    for (int j = 0; j < 8; ++j) o[j] = s[j];
  }
}

// ---------------- kernel 2/4: 256x256 8-phase GEMM (r17-exact, 74.7 us) -----
template<int EPI, int NCOL>
__global__ __launch_bounds__(512) void k_gemm2(
    const short* __restrict__ A, const short* __restrict__ B,
    const float* __restrict__ bias, const float* __restrict__ xa,
    const float* __restrict__ lb_q, const float* __restrict__ lb_v,
    short* __restrict__ out, float* __restrict__ outf)
{
  constexpr int K = DIM;            // 768, 12 K-tiles of 64
  constexpr int NWG = 49 * NCOL;
  constexpr int Qc = NWG / 8, Rc = NWG % 8;
  extern __shared__ short smem[];

  const int g = blockIdx.x;
  const int xcd = g & 7, idx = g >> 3;
  const int wgid = (xcd < Rc) ? xcd * (Qc + 1) + idx
                              : Rc * (Qc + 1) + (xcd - Rc) * Qc + idx;
  const int rm0 = (wgid / NCOL) * 256;
  const int cn0 = (wgid % NCOL) * 256;

  const int tid = threadIdx.x, lane = tid & 63, wid = tid >> 6;
  const int wm = (wid >> 2) * 128, wn = (wid & 3) * 64;
  const int fr = lane & 15, fg = lane >> 4;
  f32x4 acc[8][4] = {};

  const int srow = tid >> 2;
  const int spos = ((tid & 3) ^ ((tid >> 3) & 3)) * 8;
  const short* gaT = A + (size_t)(rm0 + srow) * K + spos;
  const short* gbT = B + (size_t)(cn0 + srow) * K + spos;
  const int swz8 = (fg ^ ((fr >> 1) & 3)) * 8;

#define STG(buf, T, s)                                                      \
  do {                                                                      \
    const short* g0 = ((s) & 1) ? gbT : gaT;                                \
    short* d0 = smem + (buf) * 32768 + ((s) & 1) * 16384                    \
                + ((s) >> 1) * 8192 + tid * 8;                              \
    g2lds16(g0 + (T) * 64 + ((s) >> 1) * 32, d0);                           \
    g2lds16(g0 + (size_t)128 * K + (T) * 64 + ((s) >> 1) * 32, d0 + 4096);  \
  } while (0)

  STG(0, 0, 0); STG(0, 0, 1); STG(0, 0, 2); STG(0, 0, 3);
  asm volatile("s_waitcnt vmcnt(0)" ::: "memory");
  __builtin_amdgcn_s_barrier();
  __builtin_amdgcn_sched_barrier(0);

  bf16x8 af[8];
  for (int T = 0; T < 12; ++T) {
    const int b = T & 1;
    const short* pA = smem + b * 32768;
    const short* pB = pA + 16384;
    #pragma unroll
    for (int q = 0; q < 4; ++q) {
      const int kh = q >> 1, jh = q & 1;
      if (jh == 0) {
        #pragma unroll
        for (int i = 0; i < 8; ++i)
          af[i] = *(const bf16x8*)&pA[kh * 8192 + (wm + i * 16 + fr) * 32 + swz8];
      }
      bf16x8 bg0 = *(const bf16x8*)&pB[kh * 8192 + (wn + (jh * 2 + 0) * 16 + fr) * 32 + swz8];
      bf16x8 bg1 = *(const bf16x8*)&pB[kh * 8192 + (wn + (jh * 2 + 1) * 16 + fr) * 32 + swz8];
      if (T + 1 < 12) {
        STG(b ^ 1, T + 1, q);
        asm volatile("s_waitcnt vmcnt(4)" ::: "memory");
      } else {
        asm volatile("s_waitcnt vmcnt(0)" ::: "memory");
      }
      __builtin_amdgcn_s_barrier();
      asm volatile("s_waitcnt lgkmcnt(0)" ::: "memory");
      __builtin_amdgcn_sched_barrier(0);
      __builtin_amdgcn_s_setprio(1);
      #pragma unroll
      for (int i = 0; i < 8; ++i) {
        acc[i][jh * 2 + 0] = mfma16(af[i], bg0, acc[i][jh * 2 + 0]);
        acc[i][jh * 2 + 1] = mfma16(af[i], bg1, acc[i][jh * 2 + 1]);
      }
      __builtin_amdgcn_s_setprio(0);
      __builtin_amdgcn_s_barrier();
    }
  }
#undef STG

  int ncol[4]; float biasv[4];
  #pragma unroll
  for (int j = 0; j < 4; ++j) {
    ncol[j] = cn0 + wn + j * 16 + fr;
    biasv[j] = bias[ncol[j]];
  }

  if (EPI == 0) {
    const int reg = cn0 / DIM;
    float lb[4][4];
    if (reg != 1) {
      const float* lbt = (reg == 0) ? lb_q : lb_v;
      #pragma unroll
      for (int j = 0; j < 4; ++j) {
        int ni = ncol[j] - reg * DIM;
        #pragma unroll
        for (int l = 0; l < 4; ++l) lb[j][l] = lbt[ni * 4 + l];
      }
    }
    #pragma unroll
    for (int i = 0; i < 8; ++i) {
      #pragma unroll
      for (int r = 0; r < 4; ++r) {
        int m = rm0 + wm + i * 16 + fg * 4 + r;
        int b_i = m / NT, p = m - b_i * NT;
        float xv0 = 0, xv1 = 0, xv2 = 0, xv3 = 0;
        if (reg != 1) {
          const float* xp = xa + m * 8 + (reg == 2 ? 4 : 0);
          xv0 = xp[0]; xv1 = xp[1]; xv2 = xp[2]; xv3 = xp[3];
        }
        #pragma unroll
        for (int j = 0; j < 4; ++j) {
          float val = acc[i][j][r] + biasv[j];
          if (reg != 1)
            val += xv0 * lb[j][0] + xv1 * lb[j][1] + xv2 * lb[j][2] + xv3 * lb[j][3];
          int ni = ncol[j] - reg * DIM;
          int head = ni >> 6, d = ni & 63;
          out[(size_t)reg * (M_ROWS * DIM)
              + ((size_t)(b_i * NH + head) * NT + p) * HD + d] = f2b(val);
        }
      }
    }
  } else {
    #pragma unroll
    for (int i = 0; i < 8; ++i)
      #pragma unroll
      for (int r = 0; r < 4; ++r) {
        int m = rm0 + wm + i * 16 + fg * 4 + r;
        #pragma unroll
        for (int j = 0; j < 4; ++j)
          outf[(size_t)m * DIM + ncol[j]] = acc[i][j][r] + biasv[j];
      }
  }
}

// ---------------- kernel 3: attention (r22 + Q-prefetch, unrolled tiles) ----
// Q loads for all owned tiles issued right after K-staging -> in flight
// during V-transpose + rel-bias phases. Tile loop unrolled x4 (compile-time
// it => static register indexing, rule #20). Arithmetic identical to r22.
__global__ __launch_bounds__(256) void k_attn(
    const short* __restrict__ qb, const short* __restrict__ kb,
    const short* __restrict__ vb, const short* __restrict__ rph,
    const short* __restrict__ rpw, short* __restrict__ ao)
{
  __shared__ short vst[64 * 256];      // V^T swizzled, 32,768 B
  __shared__ short kst[NT * 64];       // K swizzled, 25,088 B
  __shared__ short pwb[4 * 16 * 72];   // per-wave P quarter, 9,216 B
  __shared__ short relh[15 * 208];     // transposed [kh][p], 6,240 B
  __shared__ short relw[15 * 208];     // transposed [kw][p], 6,240 B
  const int tid = threadIdx.x, lane = tid & 63, wid = tid >> 6;
  const int fr = lane & 15, fg = lane >> 4;
  const int bh = blockIdx.x;
  const int b_i = bh / NH, head = bh - b_i * NH;
  const short* q0 = qb + (size_t)bh * NT * HD;
  const short* k0 = kb + (size_t)bh * NT * HD;
  const short* v0 = vb + (size_t)bh * NT * HD;

  // async K staging FIRST
  for (int t = tid; t < NT * 8; t += 256) {
    int row = t >> 3, slot = t & 7;
    g2lds16(k0 + row * 64 + ((slot ^ (row & 7)) * 8), &kst[t * 8]);
  }
  // Q prefetch for all owned tiles (in flight during V/rel phases)
  bf16x8 qpre[4][2];
  #pragma unroll
  for (int it = 0; it < 4; ++it) {
    const int t = wid + it * 4;
    const int arow = t * 16 + fr;
    qpre[it][0] = (bf16x8){0,0,0,0,0,0,0,0};
    qpre[it][1] = (bf16x8){0,0,0,0,0,0,0,0};
    if (t < 13 && arow < NT) {
      qpre[it][0] = *(const bf16x8*)(q0 + arow * HD + fg * 8);
      qpre[it][1] = *(const bf16x8*)(q0 + arow * HD + 32 + fg * 8);
    }
  }

  for (int i = tid; i < 64 * 12; i += 256) {
    int row = i / 12, c = 196 + (i - (i / 12) * 12);
    vst[row * 256 + (c ^ (((row >> 2) & 7) * 8))] = 0;
  }
  for (int t = tid; t < NT * 8; t += 256) {
    int p = t >> 3, d0 = (t & 7) * 8;
    bf16x8 vv = *(const bf16x8*)(v0 + p * HD + d0);
    #pragma unroll
    for (int j = 0; j < 8; ++j)
      vst[(d0 + j) * 256 + (p ^ ((((d0 + j) >> 2) & 7) * 8))] = vv[j];
  }
  if (wid > 0) {
    for (int job = wid - 1; job < 28; job += 3) {
      const int isW = job >= 14 ? 1 : 0;
      const int fx = isW ? job - 14 : job;
      const int qrow = isW ? fr * 14 + fx : fx * 14 + fr;
      const bool aok = fr < 14;
      const short* rp = isW ? rpw : rph;
      int ridx = fx - fr + 13;
      ridx = ridx < 0 ? 0 : (ridx > 26 ? 26 : ridx);
      f32x4 racc = {0.f, 0.f, 0.f, 0.f};
      #pragma unroll
      for (int ks = 0; ks < 2; ++ks) {
        bf16x8 afr = {0,0,0,0,0,0,0,0};
        if (aok) afr = *(const bf16x8*)(q0 + qrow * HD + ks * 32 + fg * 8);
        bf16x8 bfr = *(const bf16x8*)(rp + ridx * HD + ks * 32 + fg * 8);
        racc = mfma16(afr, bfr, racc);
      }
      #pragma unroll
      for (int r = 0; r < 4; ++r) {
        int rr = fg * 4 + r;
        if (rr < 14 && fr < 14) {
          int p = isW ? rr * 14 + fx : fx * 14 + rr;
          (isW ? relw : relh)[fr * 208 + p] = f2b(racc[r]);
        }
      }
    }
  }
  __syncthreads();   // drains vmcnt(0): kst staging complete

  const float scale = 0.125f;
  const int p0 = fg ^ (fr & 7);
  const int p1 = (fg + 4) ^ (fr & 7);
  #pragma unroll
  for (int it = 0; it < 4; ++it) {
    const int t = wid + it * 4;
    if (t < 13) {
    const int m0 = t * 16;
    const int p0g = m0 + fg * 4;
    f32x4 sc[13] = {};
    #pragma unroll
    for (int ct = 0; ct < 13; ++ct) {
      int brow = ct * 16 + fr;
      bf16x8 bk0 = {0,0,0,0,0,0,0,0}, bk1 = {0,0,0,0,0,0,0,0};
      if (brow < NT) {
        bk0 = *(const bf16x8*)&kst[brow * 64 + p0 * 8];
        bk1 = *(const bf16x8*)&kst[brow * 64 + p1 * 8];
      }
      sc[ct] = mfma16(qpre[it][0], bk0, sc[ct]);
      sc[ct] = mfma16(qpre[it][1], bk1, sc[ct]);
    }
    float rsum[4] = {0.f, 0.f, 0.f, 0.f};
    #pragma unroll
    for (int ct = 0; ct < 13; ++ct) {
      int kk = ct * 16 + fr;
      int kh = kk / 14, kw = kk - kh * 14;
      short4 h4 = *(const short4*)&relh[kh * 208 + p0g];
      short4 w4 = *(const short4*)&relw[kw * 208 + p0g];
      #pragma unroll
      for (int r = 0; r < 4; ++r) {
        int p = p0g + r;
        short hs = (r == 0) ? h4.x : (r == 1) ? h4.y : (r == 2) ? h4.z : h4.w;
        short ws = (r == 0) ? w4.x : (r == 1) ? w4.y : (r == 2) ? w4.z : w4.w;
        float e;
        if (kk < NT && p < NT)
          e = __expf(sc[ct][r] * scale + b2f(hs) + b2f(ws));
        else
          e = 0.f;
        sc[ct][r] = e;
        rsum[r] += e;
      }
    }
    #pragma unroll
    for (int r = 0; r < 4; ++r) {
      rsum[r] += __shfl_xor(rsum[r], 1);
      rsum[r] += __shfl_xor(rsum[r], 2);
      rsum[r] += __shfl_xor(rsum[r], 4);
      rsum[r] += __shfl_xor(rsum[r], 8);
    }

    f32x4 oacc[4] = {};
    #pragma unroll
    for (int qd = 0; qd < 4; ++qd) {
      const int ctb = qd * 4;
      const int nct = (qd == 3) ? 1 : 4;
      #pragma unroll
      for (int cl = 0; cl < 4; ++cl) {
        if (cl < nct) {
          #pragma unroll
          for (int r = 0; r < 4; ++r)
            pwb[(wid * 16 + fg * 4 + r) * 72 + cl * 16 + fr] =
                f2b(sc[ctb + cl][r]);
        }
      }
      const int nks = (qd == 3) ? 1 : 2;
      #pragma unroll
      for (int ks = 0; ks < 2; ++ks) {
        if (ks < nks) {
          const bool hi = (qd == 3) && (fg >= 2);
          bf16x8 pa = {0,0,0,0,0,0,0,0};
          if (!hi) pa = *(const bf16x8*)&pwb[(wid * 16 + fr) * 72 + ks * 32 + fg * 8];
          const int c = qd * 64 + ks * 32 + fg * 8;
          #pragma unroll
          for (int dt = 0; dt < 4; ++dt) {
            bf16x8 vv = {0,0,0,0,0,0,0,0};
            if (!hi)
              vv = *(const bf16x8*)&vst[(fr * 4 + dt) * 256 + (c ^ ((fr & 7) * 8))];
            oacc[dt] = mfma16(pa, vv, oacc[dt]);
          }
        }
      }
    }
    #pragma unroll
    for (int r = 0; r < 4; ++r) {
      int p = p0g + r;
      if (p < NT) {
        float inv = 1.0f / rsum[r];
        size_t base = ((size_t)(b_i * NT + p)) * DIM + head * HD + fr * 4;
        short4 o4 = { f2b(oacc[0][r] * inv), f2b(oacc[1][r] * inv),
                      f2b(oacc[2][r] * inv), f2b(oacc[3][r] * inv) };
        *(short4*)&ao[base] = o4;
      }
    }
    }  // t < 13
  }
}

// ---------------------------------------------------------------------------
extern "C" void kernel_launch(void* const* d_in, const int* in_sizes, int n_in,
                              void* d_out, int out_size, void* d_ws, size_t ws_size,
                              hipStream_t stream) {
  // Resolve inputs BY SIZE (robust to pytree ordering).
  const float *x = nullptr, *qkv_w = nullptr, *qkv_b = nullptr,
              *proj_w = nullptr, *proj_b = nullptr, *rph = nullptr,
              *rpw = nullptr;
  const float* c3072[4] = {nullptr, nullptr, nullptr, nullptr};
  int n3072 = 0, n1728 = 0;
  for (int i = 0; i < n_in; ++i) {
    const float* p = (const float*)d_in[i];
    switch (in_sizes[i]) {
      case 9633792: x = p; break;
      case 1769472: qkv_w = p; break;
      case 2304:    qkv_b = p; break;
      case 589824:  proj_w = p; break;
      case 768:     proj_b = p; break;
      case 3072:    if (n3072 < 4) c3072[n3072++] = p; break;
      case 1728:    { if (n1728 == 0) rph = p; else rpw = p; ++n1728; } break;
      default: break;
    }
  }
  const bool alpha = (n_in >= 1 && in_sizes[n_in - 1] == 9633792);
  const float* la_q = c3072[0];
  const float* lb_q = alpha ? c3072[2] : c3072[1];
  const float* la_v = alpha ? c3072[1] : c3072[2];
  const float* lb_v = c3072[3];

  float* out = (float*)d_out;   // FP32 output (reference dtype)

  char* ws = (char*)d_ws;
  float* xa   = (float*)ws;                                   // 401,408 B
  short* qkvb = (short*)(ws + 401408);                        // 57,802,752 B
  short* q_   = qkvb;
  short* k_   = qkvb + (size_t)M_ROWS * DIM;
  short* v_   = qkvb + (size_t)2 * M_ROWS * DIM;
  short* cvt  = (short*)(ws + 401408 + 57802752);             // 23,993,088 B
  short* xb      = cvt;                 // 9,633,792 shorts (from k_pre)
  short* qkv_wb  = cvt + 9633792;       // 1,769,472
  short* proj_wb = cvt + 11403264;      //   589,824
  short* rphb    = cvt + 11993088;      //     1,728
  short* rpwb    = cvt + 11994816;      //     1,728
  short* ao = xb;  // alias: x_bf16 dead after qkv gemm; sizes identical

  CvtArgs ca;
  ca.src[0] = qkv_w;  ca.n4[0] = 1769472 / 4;  ca.off[0] = 9633792;
  ca.src[1] = proj_w; ca.n4[1] =  589824 / 4;  ca.off[1] = 11403264;
  ca.src[2] = rph;    ca.n4[2] =    1728 / 4;  ca.off[2] = 11993088;
  ca.src[3] = rpw;    ca.n4[3] =    1728 / 4;  ca.off[3] = 11994816;

  hipFuncSetAttribute((const void*)k_gemm2<0, 9>,
                      hipFuncAttributeMaxDynamicSharedMemorySize, 131072);
  hipFuncSetAttribute((const void*)k_gemm2<1, 3>,
                      hipFuncAttributeMaxDynamicSharedMemorySize, 131072);

  k_pre<<<3648, 256, 0, stream>>>(x, la_q, la_v, xa, xb, ca, cvt);
  k_gemm2<0, 9><<<441, 512, 131072, stream>>>(xb, qkv_wb, qkv_b, xa, lb_q,
                                              lb_v, qkvb, nullptr);
  k_attn<<<768, 256, 0, stream>>>(q_, k_, v_, rphb, rpwb, ao);
  k_gemm2<1, 3><<<147, 512, 131072, stream>>>(ao, proj_wb, proj_b, nullptr,
                                              nullptr, nullptr, nullptr, out);
}

// Round 24
// 173.587 us; speedup vs baseline: 1.0136x; 1.0136x over previous
//
#include <hip/hip_runtime.h>
#include <stdint.h>

#define DIM   768
#define NH    12
#define HD    64
#define NT    196      // 14*14 tokens
#define M_ROWS 12544   // 64*196

typedef __attribute__((ext_vector_type(8))) short bf16x8;
typedef __attribute__((ext_vector_type(4))) float f32x4;

__device__ __forceinline__ float b2f(short s) {
  union { unsigned u; float f; } c;
  c.u = ((unsigned)(unsigned short)s) << 16;
  return c.f;
}
__device__ __forceinline__ short f2b(float f) {
  union { float f; unsigned u; } c; c.f = f;
  unsigned u = c.u;
  u += 0x7fffu + ((u >> 16) & 1u);   // RNE
  return (short)(u >> 16);
}

__device__ __forceinline__ f32x4 mfma16(bf16x8 a, bf16x8 b, f32x4 c) {
  return __builtin_amdgcn_mfma_f32_16x16x32_bf16(a, b, c, 0, 0, 0);
}

__device__ __forceinline__ void g2lds16(const short* g, short* l) {
  __builtin_amdgcn_global_load_lds(
      (const __attribute__((address_space(1))) void*)g,
      (__attribute__((address_space(3))) void*)l, 16, 0, 0);
}

// -------- kernel 1: fused pre-stage -----------------------------------------
struct CvtArgs { const float* src[4]; int n4[4]; int off[4]; };

__global__ __launch_bounds__(256) void k_pre(
    const float* __restrict__ x, const float* __restrict__ la_q,
    const float* __restrict__ la_v, float* __restrict__ xa,
    short* __restrict__ xb, CvtArgs a, short* __restrict__ cvtdst)
{
  const int bid = blockIdx.x;
  const int tid = threadIdx.x;
  if (bid >= 3136) {
    const int gt = (bid - 3136) * 256 + tid;
    const int stride = 512 * 256;
    #pragma unroll
    for (int s = 0; s < 4; ++s) {
      const float4* sp = (const float4*)a.src[s];
      short4* dp = (short4*)(cvtdst + a.off[s]);
      const int n4 = a.n4[s];
      for (int i = gt; i < n4; i += stride) {
        float4 v = sp[i];
        short4 o = { f2b(v.x), f2b(v.y), f2b(v.z), f2b(v.w) };
        dp[i] = o;
      }
    }
    return;
  }
  __shared__ float sla[8][DIM];
  for (int i = tid; i < 8 * DIM; i += 256) {
    int j = i / DIM, c = i - j * DIM;
    sla[j][c] = (j < 4) ? la_q[j * DIM + c] : la_v[(j - 4) * DIM + c];
  }
  __syncthreads();
  const int lane = tid & 63, wid = tid >> 6;
  const int m = bid * 4 + wid;
  const float4* xr = (const float4*)(x + (size_t)m * DIM);
  short4* xbr = (short4*)(xb + (size_t)m * DIM);
  float s[8] = {};
  #pragma unroll
  for (int i = 0; i < 3; ++i) {
    float4 xv = xr[lane + 64 * i];
    short4 o = { f2b(xv.x), f2b(xv.y), f2b(xv.z), f2b(xv.w) };
    xbr[lane + 64 * i] = o;
    int c = (lane + 64 * i) * 4;
    #pragma unroll
    for (int j = 0; j < 8; ++j)
      s[j] += xv.x * sla[j][c] + xv.y * sla[j][c + 1]
            + xv.z * sla[j][c + 2] + xv.w * sla[j][c + 3];
  }
  #pragma unroll
  for (int j = 0; j < 8; ++j) {
    #pragma unroll
    for (int off = 32; off; off >>= 1) s[j] += __shfl_xor(s[j], off);
  }
  if (lane == 0) {
    float* o = xa + m * 8;
    #pragma unroll
    for (int j = 0; j < 8; ++j) o[j] = s[j];
  }
}

// ---------------- kernel 2/4: 256x256 GEMM, 2-phase-per-K-tile --------------
// r17 pipeline with the 4 sub-phases merged to 2 (32 MFMA per barrier pair,
// half the barriers). vmcnt(4) retires the previous phase's 4-load quad;
// stage->use and overwrite orderings re-derived identical to r17.
// Same K-accumulation order => bit-identical output.
template<int EPI, int NCOL>
__global__ __launch_bounds__(512) void k_gemm2(
    const short* __restrict__ A, const short* __restrict__ B,
    const float* __restrict__ bias, const float* __restrict__ xa,
    const float* __restrict__ lb_q, const float* __restrict__ lb_v,
    short* __restrict__ out, float* __restrict__ outf)
{
  constexpr int K = DIM;            // 768, 12 K-tiles of 64
  constexpr int NWG = 49 * NCOL;
  constexpr int Qc = NWG / 8, Rc = NWG % 8;
  extern __shared__ short smem[];

  const int g = blockIdx.x;
  const int xcd = g & 7, idx = g >> 3;
  const int wgid = (xcd < Rc) ? xcd * (Qc + 1) + idx
                              : Rc * (Qc + 1) + (xcd - Rc) * Qc + idx;
  const int rm0 = (wgid / NCOL) * 256;
  const int cn0 = (wgid % NCOL) * 256;

  const int tid = threadIdx.x, lane = tid & 63, wid = tid >> 6;
  const int wm = (wid >> 2) * 128, wn = (wid & 3) * 64;
  const int fr = lane & 15, fg = lane >> 4;
  f32x4 acc[8][4] = {};

  const int srow = tid >> 2;
  const int spos = ((tid & 3) ^ ((tid >> 3) & 3)) * 8;
  const short* gaT = A + (size_t)(rm0 + srow) * K + spos;
  const short* gbT = B + (size_t)(cn0 + srow) * K + spos;
  const int swz8 = (fg ^ ((fr >> 1) & 3)) * 8;

#define STG(buf, T, s)                                                      \
  do {                                                                      \
    const short* g0 = ((s) & 1) ? gbT : gaT;                                \
    short* d0 = smem + (buf) * 32768 + ((s) & 1) * 16384                    \
                + ((s) >> 1) * 8192 + tid * 8;                              \
    g2lds16(g0 + (T) * 64 + ((s) >> 1) * 32, d0);                           \
    g2lds16(g0 + (size_t)128 * K + (T) * 64 + ((s) >> 1) * 32, d0 + 4096);  \
  } while (0)

  STG(0, 0, 0); STG(0, 0, 1); STG(0, 0, 2); STG(0, 0, 3);
  asm volatile("s_waitcnt vmcnt(0)" ::: "memory");
  __builtin_amdgcn_s_barrier();
  __builtin_amdgcn_sched_barrier(0);

  for (int T = 0; T < 12; ++T) {
    const int b = T & 1;
    const short* pA = smem + b * 32768;
    const short* pB = pA + 16384;
    #pragma unroll
    for (int h = 0; h < 2; ++h) {
      bf16x8 af[8], bg[4];
      #pragma unroll
      for (int i = 0; i < 8; ++i)
        af[i] = *(const bf16x8*)&pA[h * 8192 + (wm + i * 16 + fr) * 32 + swz8];
      #pragma unroll
      for (int j = 0; j < 4; ++j)
        bg[j] = *(const bf16x8*)&pB[h * 8192 + (wn + j * 16 + fr) * 32 + swz8];
      if (T + 1 < 12) {
        STG(b ^ 1, T + 1, h * 2);
        STG(b ^ 1, T + 1, h * 2 + 1);
        asm volatile("s_waitcnt vmcnt(4)" ::: "memory");
      } else {
        asm volatile("s_waitcnt vmcnt(0)" ::: "memory");
      }
      __builtin_amdgcn_s_barrier();
      asm volatile("s_waitcnt lgkmcnt(0)" ::: "memory");
      __builtin_amdgcn_sched_barrier(0);
      __builtin_amdgcn_s_setprio(1);
      #pragma unroll
      for (int i = 0; i < 8; ++i)
        #pragma unroll
        for (int j = 0; j < 4; ++j)
          acc[i][j] = mfma16(af[i], bg[j], acc[i][j]);
      __builtin_amdgcn_s_setprio(0);
      __builtin_amdgcn_s_barrier();
    }
  }
#undef STG

  int ncol[4]; float biasv[4];
  #pragma unroll
  for (int j = 0; j < 4; ++j) {
    ncol[j] = cn0 + wn + j * 16 + fr;
    biasv[j] = bias[ncol[j]];
  }

  if (EPI == 0) {
    const int reg = cn0 / DIM;
    float lb[4][4];
    if (reg != 1) {
      const float* lbt = (reg == 0) ? lb_q : lb_v;
      #pragma unroll
      for (int j = 0; j < 4; ++j) {
        int ni = ncol[j] - reg * DIM;
        #pragma unroll
        for (int l = 0; l < 4; ++l) lb[j][l] = lbt[ni * 4 + l];
      }
    }
    #pragma unroll
    for (int i = 0; i < 8; ++i) {
      #pragma unroll
      for (int r = 0; r < 4; ++r) {
        int m = rm0 + wm + i * 16 + fg * 4 + r;
        int b_i = m / NT, p = m - b_i * NT;
        float xv0 = 0, xv1 = 0, xv2 = 0, xv3 = 0;
        if (reg != 1) {
          const float* xp = xa + m * 8 + (reg == 2 ? 4 : 0);
          xv0 = xp[0]; xv1 = xp[1]; xv2 = xp[2]; xv3 = xp[3];
        }
        #pragma unroll
        for (int j = 0; j < 4; ++j) {
          float val = acc[i][j][r] + biasv[j];
          if (reg != 1)
            val += xv0 * lb[j][0] + xv1 * lb[j][1] + xv2 * lb[j][2] + xv3 * lb[j][3];
          int ni = ncol[j] - reg * DIM;
          int head = ni >> 6, d = ni & 63;
          out[(size_t)reg * (M_ROWS * DIM)
              + ((size_t)(b_i * NH + head) * NT + p) * HD + d] = f2b(val);
        }
      }
    }
  } else {
    #pragma unroll
    for (int i = 0; i < 8; ++i)
      #pragma unroll
      for (int r = 0; r < 4; ++r) {
        int m = rm0 + wm + i * 16 + fg * 4 + r;
        #pragma unroll
        for (int j = 0; j < 4; ++j)
          outf[(size_t)m * DIM + ncol[j]] = acc[i][j][r] + biasv[j];
      }
  }
}

// ---------------- kernel 3: attention (r22-exact) ---------------------------
__global__ __launch_bounds__(256) void k_attn(
    const short* __restrict__ qb, const short* __restrict__ kb,
    const short* __restrict__ vb, const short* __restrict__ rph,
    const short* __restrict__ rpw, short* __restrict__ ao)
{
  __shared__ short vst[64 * 256];      // V^T swizzled, 32,768 B
  __shared__ short kst[NT * 64];       // K swizzled, 25,088 B
  __shared__ short pwb[4 * 16 * 72];   // per-wave P quarter, 9,216 B
  __shared__ short relh[15 * 208];     // transposed [kh][p], 6,240 B
  __shared__ short relw[15 * 208];     // transposed [kw][p], 6,240 B
  const int tid = threadIdx.x, lane = tid & 63, wid = tid >> 6;
  const int fr = lane & 15, fg = lane >> 4;
  const int bh = blockIdx.x;
  const int b_i = bh / NH, head = bh - b_i * NH;
  const short* q0 = qb + (size_t)bh * NT * HD;
  const short* k0 = kb + (size_t)bh * NT * HD;
  const short* v0 = vb + (size_t)bh * NT * HD;

  for (int t = tid; t < NT * 8; t += 256) {
    int row = t >> 3, slot = t & 7;
    g2lds16(k0 + row * 64 + ((slot ^ (row & 7)) * 8), &kst[t * 8]);
  }

  for (int i = tid; i < 64 * 12; i += 256) {
    int row = i / 12, c = 196 + (i - (i / 12) * 12);
    vst[row * 256 + (c ^ (((row >> 2) & 7) * 8))] = 0;
  }
  for (int t = tid; t < NT * 8; t += 256) {
    int p = t >> 3, d0 = (t & 7) * 8;
    bf16x8 vv = *(const bf16x8*)(v0 + p * HD + d0);
    #pragma unroll
    for (int j = 0; j < 8; ++j)
      vst[(d0 + j) * 256 + (p ^ ((((d0 + j) >> 2) & 7) * 8))] = vv[j];
  }
  if (wid > 0) {
    for (int job = wid - 1; job < 28; job += 3) {
      const int isW = job >= 14 ? 1 : 0;
      const int fx = isW ? job - 14 : job;
      const int qrow = isW ? fr * 14 + fx : fx * 14 + fr;
      const bool aok = fr < 14;
      const short* rp = isW ? rpw : rph;
      int ridx = fx - fr + 13;
      ridx = ridx < 0 ? 0 : (ridx > 26 ? 26 : ridx);
      f32x4 racc = {0.f, 0.f, 0.f, 0.f};
      #pragma unroll
      for (int ks = 0; ks < 2; ++ks) {
        bf16x8 afr = {0,0,0,0,0,0,0,0};
        if (aok) afr = *(const bf16x8*)(q0 + qrow * HD + ks * 32 + fg * 8);
        bf16x8 bfr = *(const bf16x8*)(rp + ridx * HD + ks * 32 + fg * 8);
        racc = mfma16(afr, bfr, racc);
      }
      #pragma unroll
      for (int r = 0; r < 4; ++r) {
        int rr = fg * 4 + r;
        if (rr < 14 && fr < 14) {
          int p = isW ? rr * 14 + fx : fx * 14 + rr;
          (isW ? relw : relh)[fr * 208 + p] = f2b(racc[r]);
        }
      }
    }
  }
  __syncthreads();   // drains vmcnt(0): kst staging complete

  const float scale = 0.125f;
  const int p0 = fg ^ (fr & 7);
  const int p1 = (fg + 4) ^ (fr & 7);
  for (int t = wid; t < 13; t += 4) {
    const int m0 = t * 16;
    const int p0g = m0 + fg * 4;
    bf16x8 aq0 = {0,0,0,0,0,0,0,0}, aq1 = {0,0,0,0,0,0,0,0};
    {
      int arow = m0 + fr;
      if (arow < NT) {
        aq0 = *(const bf16x8*)(q0 + arow * HD + fg * 8);
        aq1 = *(const bf16x8*)(q0 + arow * HD + 32 + fg * 8);
      }
    }
    f32x4 sc[13] = {};
    #pragma unroll
    for (int ct = 0; ct < 13; ++ct) {
      int brow = ct * 16 + fr;
      bf16x8 bk0 = {0,0,0,0,0,0,0,0}, bk1 = {0,0,0,0,0,0,0,0};
      if (brow < NT) {
        bk0 = *(const bf16x8*)&kst[brow * 64 + p0 * 8];
        bk1 = *(const bf16x8*)&kst[brow * 64 + p1 * 8];
      }
      sc[ct] = mfma16(aq0, bk0, sc[ct]);
      sc[ct] = mfma16(aq1, bk1, sc[ct]);
    }
    float rsum[4] = {0.f, 0.f, 0.f, 0.f};
    #pragma unroll
    for (int ct = 0; ct < 13; ++ct) {
      int kk = ct * 16 + fr;
      int kh = kk / 14, kw = kk - kh * 14;
      short4 h4 = *(const short4*)&relh[kh * 208 + p0g];
      short4 w4 = *(const short4*)&relw[kw * 208 + p0g];
      #pragma unroll
      for (int r = 0; r < 4; ++r) {
        int p = p0g + r;
        short hs = (r == 0) ? h4.x : (r == 1) ? h4.y : (r == 2) ? h4.z : h4.w;
        short ws = (r == 0) ? w4.x : (r == 1) ? w4.y : (r == 2) ? w4.z : w4.w;
        float e;
        if (kk < NT && p < NT)
          e = __expf(sc[ct][r] * scale + b2f(hs) + b2f(ws));
        else
          e = 0.f;
        sc[ct][r] = e;
        rsum[r] += e;
      }
    }
    #pragma unroll
    for (int r = 0; r < 4; ++r) {
      rsum[r] += __shfl_xor(rsum[r], 1);
      rsum[r] += __shfl_xor(rsum[r], 2);
      rsum[r] += __shfl_xor(rsum[r], 4);
      rsum[r] += __shfl_xor(rsum[r], 8);
    }

    f32x4 oacc[4] = {};
    #pragma unroll
    for (int qd = 0; qd < 4; ++qd) {
      const int ctb = qd * 4;
      const int nct = (qd == 3) ? 1 : 4;
      #pragma unroll
      for (int cl = 0; cl < 4; ++cl) {
        if (cl < nct) {
          #pragma unroll
          for (int r = 0; r < 4; ++r)
            pwb[(wid * 16 + fg * 4 + r) * 72 + cl * 16 + fr] =
                f2b(sc[ctb + cl][r]);
        }
      }
      const int nks = (qd == 3) ? 1 : 2;
      #pragma unroll
      for (int ks = 0; ks < 2; ++ks) {
        if (ks < nks) {
          const bool hi = (qd == 3) && (fg >= 2);
          bf16x8 pa = {0,0,0,0,0,0,0,0};
          if (!hi) pa = *(const bf16x8*)&pwb[(wid * 16 + fr) * 72 + ks * 32 + fg * 8];
          const int c = qd * 64 + ks * 32 + fg * 8;
          #pragma unroll
          for (int dt = 0; dt < 4; ++dt) {
            bf16x8 vv = {0,0,0,0,0,0,0,0};
            if (!hi)
              vv = *(const bf16x8*)&vst[(fr * 4 + dt) * 256 + (c ^ ((fr & 7) * 8))];
            oacc[dt] = mfma16(pa, vv, oacc[dt]);
          }
        }
      }
    }
    #pragma unroll
    for (int r = 0; r < 4; ++r) {
      int p = p0g + r;
      if (p < NT) {
        float inv = 1.0f / rsum[r];
        size_t base = ((size_t)(b_i * NT + p)) * DIM + head * HD + fr * 4;
        short4 o4 = { f2b(oacc[0][r] * inv), f2b(oacc[1][r] * inv),
                      f2b(oacc[2][r] * inv), f2b(oacc[3][r] * inv) };
        *(short4*)&ao[base] = o4;
      }
    }
  }
}

// ---------------------------------------------------------------------------
extern "C" void kernel_launch(void* const* d_in, const int* in_sizes, int n_in,
                              void* d_out, int out_size, void* d_ws, size_t ws_size,
                              hipStream_t stream) {
  // Resolve inputs BY SIZE (robust to pytree ordering).
  const float *x = nullptr, *qkv_w = nullptr, *qkv_b = nullptr,
              *proj_w = nullptr, *proj_b = nullptr, *rph = nullptr,
              *rpw = nullptr;
  const float* c3072[4] = {nullptr, nullptr, nullptr, nullptr};
  int n3072 = 0, n1728 = 0;
  for (int i = 0; i < n_in; ++i) {
    const float* p = (const float*)d_in[i];
    switch (in_sizes[i]) {
      case 9633792: x = p; break;
      case 1769472: qkv_w = p; break;
      case 2304:    qkv_b = p; break;
      case 589824:  proj_w = p; break;
      case 768:     proj_b = p; break;
      case 3072:    if (n3072 < 4) c3072[n3072++] = p; break;
      case 1728:    { if (n1728 == 0) rph = p; else rpw = p; ++n1728; } break;
      default: break;
    }
  }
  const bool alpha = (n_in >= 1 && in_sizes[n_in - 1] == 9633792);
  const float* la_q = c3072[0];
  const float* lb_q = alpha ? c3072[2] : c3072[1];
  const float* la_v = alpha ? c3072[1] : c3072[2];
  const float* lb_v = c3072[3];

  float* out = (float*)d_out;   // FP32 output (reference dtype)

  char* ws = (char*)d_ws;
  float* xa   = (float*)ws;                                   // 401,408 B
  short* qkvb = (short*)(ws + 401408);                        // 57,802,752 B
  short* q_   = qkvb;
  short* k_   = qkvb + (size_t)M_ROWS * DIM;
  short* v_   = qkvb + (size_t)2 * M_ROWS * DIM;
  short* cvt  = (short*)(ws + 401408 + 57802752);             // 23,993,088 B
  short* xb      = cvt;                 // 9,633,792 shorts (from k_pre)
  short* qkv_wb  = cvt + 9633792;       // 1,769,472
  short* proj_wb = cvt + 11403264;      //   589,824
  short* rphb    = cvt + 11993088;      //     1,728
  short* rpwb    = cvt + 11994816;      //     1,728
  short* ao = xb;  // alias: x_bf16 dead after qkv gemm; sizes identical

  CvtArgs ca;
  ca.src[0] = qkv_w;  ca.n4[0] = 1769472 / 4;  ca.off[0] = 9633792;
  ca.src[1] = proj_w; ca.n4[1] =  589824 / 4;  ca.off[1] = 11403264;
  ca.src[2] = rph;    ca.n4[2] =    1728 / 4;  ca.off[2] = 11993088;
  ca.src[3] = rpw;    ca.n4[3] =    1728 / 4;  ca.off[3] = 11994816;

  hipFuncSetAttribute((const void*)k_gemm2<0, 9>,
                      hipFuncAttributeMaxDynamicSharedMemorySize, 131072);
  hipFuncSetAttribute((const void*)k_gemm2<1, 3>,
                      hipFuncAttributeMaxDynamicSharedMemorySize, 131072);

  k_pre<<<3648, 256, 0, stream>>>(x, la_q, la_v, xa, xb, ca, cvt);
  k_gemm2<0, 9><<<441, 512, 131072, stream>>>(xb, qkv_wb, qkv_b, xa, lb_q,
                                              lb_v, qkvb, nullptr);
  k_attn<<<768, 256, 0, stream>>>(q_, k_, v_, rphb, rpwb, ao);
  k_gemm2<1, 3><<<147, 512, 131072, stream>>>(ao, proj_wb, proj_b, nullptr,
                                              nullptr, nullptr, nullptr, out);
}